// Round 6
// baseline (114.273 us; speedup 1.0000x reference)
//
#include <hip/hip_runtime.h>
#include <cmath>

#define WAVE 64
#define TPB  256
#define FTPB 1024

__device__ __forceinline__ float fastrcp(float x) { return __builtin_amdgcn_rcpf(x); }

__device__ __forceinline__ unsigned sortable_u32(float f) {
    unsigned b = __float_as_uint(f);
    return (b & 0x80000000u) ? ~b : (b | 0x80000000u);
}

// mask may arrive as u8 bool, i32, or f32 — probe byte pattern.
__device__ __forceinline__ int mask_mode(const void* maskp) {
    const unsigned char* mb = (const unsigned char*)maskp;
    unsigned char b0 = mb[0], b1 = mb[1];
    if (b0 != 0 && b1 != 0) return 0;   // u8
    if (b0 != 0) return 1;              // i32
    return 2;                           // f32
}
__device__ __forceinline__ float mask_v(const void* maskp, int t, int mode) {
    if (mode == 0) return ((const unsigned char*)maskp)[t] ? 1.0f : 0.0f;
    if (mode == 1) return ((const int*)maskp)[t] ? 1.0f : 0.0f;
    return (((const float*)maskp)[t] != 0.0f) ? 1.0f : 0.0f;
}
__device__ __forceinline__ int midx(int m, int nsh, int N) {
    return (nsh >= 0) ? (m >> nsh) : (m / N);
}

// ---------------- prep: convert pred, areas, v, per-64-chunk mask bits -----
__global__ __launch_bounds__(TPB) void prep_kernel(
        const float4* __restrict__ pred, const float4* __restrict__ tgt,
        const void* __restrict__ maskp, int M, int nsh, int N,
        float4* __restrict__ convS, float* __restrict__ areaS,
        float* __restrict__ areaT, float* __restrict__ vv,
        unsigned long long* __restrict__ cmask) {
    int m = blockIdx.x * blockDim.x + threadIdx.x;
    if (m >= M) return;
    float4 p = pred[m];
    float x1 = p.x - 0.5f * p.z, y1 = p.y - 0.5f * p.w;
    float x2 = p.x + 0.5f * p.z, y2 = p.y + 0.5f * p.w;
    convS[m] = make_float4(x1, y1, x2, y2);
    areaS[m] = (x2 - x1) * (y2 - y1);
    float4 t = tgt[m];
    areaT[m] = (t.z - t.x) * (t.w - t.y);
    float vm = mask_v(maskp, midx(m, nsh, N), mask_mode(maskp));
    vv[m] = vm;
    unsigned long long bal = __ballot(vm > 0.0f);
    if ((threadIdx.x & (WAVE - 1)) == 0) cmask[m >> 6] = bal;
}

// ---------------------------------------------------------------------------
// Fused pass, two lane-local roles split by blockIdx:
//  rows-role: 256 rows per block (lane-resident), 64 cols via SCALAR loads
//             (base derived from blockIdx only -> provably wave-uniform).
//             Row-argmax lane-local: ascending j + strict > = exact first-max.
//  cols-role: 256 cols per block (lane-resident), 64 rows via scalar loads.
//             Col-sum lane-local fma. h = giou+1 (corrected in finalize).
// No LDS, no shuffles, no atomics in the hot loop.
// ---------------------------------------------------------------------------
__global__ __launch_bounds__(TPB) void pass_kernel(
        const float4* __restrict__ tgt, const float* __restrict__ areaT,
        const float4* __restrict__ convS, const float* __restrict__ areaS,
        const unsigned long long* __restrict__ cmask, int M, int rowBlocks,
        unsigned long long* __restrict__ keypart, float* __restrict__ colpart) {
    const int C   = M >> 6;                 // 64-wide chunks
    const int tid = threadIdx.x;

    if ((int)blockIdx.x < rowBlocks) {
        const int rb = blockIdx.x / C;      // row block (256 rows)
        const int cc = blockIdx.x % C;      // column chunk (64 cols) — uniform
        const int r  = rb * TPB + tid;
        float4 a  = tgt[r];
        float  aA = areaT[r];
        const unsigned long long cm = cmask[cc];
        const float4* __restrict__ bc = convS + (size_t)cc * 64;   // block-uniform
        const float*  __restrict__ ba = areaS + (size_t)cc * 64;

        float best = -INFINITY;
        int   bidx = 0;
#pragma unroll 8
        for (int j = 0; j < 64; ++j) {
            if (!((cm >> j) & 1ull)) continue;          // uniform scalar skip
            float4 b  = bc[j];                          // s_load (broadcast)
            float  aB = ba[j];
            float ltx = fmaxf(a.x, b.x), lty = fmaxf(a.y, b.y);
            float rbx = fminf(a.z, b.z), rby = fminf(a.w, b.w);
            float w = fmaxf(rbx - ltx, 0.0f), h = fmaxf(rby - lty, 0.0f);
            float inter = w * h;
            float uni = aA + aB - inter;
            float cx1 = fminf(a.x, b.x), cy1 = fminf(a.y, b.y);
            float cx2 = fmaxf(a.z, b.z), cy2 = fmaxf(a.w, b.w);
            float areaC = (cx2 - cx1) * (cy2 - cy1);    // >= 0 by construction
            float hval = fmaf(uni, fastrcp(areaC), inter * fastrcp(uni));
            if (hval > best) { best = hval; bidx = cc * 64 + j; }
        }
        unsigned long long key = ((unsigned long long)sortable_u32(best) << 32)
                               | (unsigned)(~bidx);
        keypart[(size_t)cc * M + r] = key;              // coalesced 8B
    } else {
        const int bb2 = blockIdx.x - rowBlocks;
        const int cb = bb2 / C;                         // col block (256 cols)
        const int rc = bb2 % C;                         // row chunk (64 rows) — uniform
        const int c  = cb * TPB + tid;
        float4 b  = convS[c];
        float  aB = areaS[c];
        const unsigned long long rm = cmask[rc];
        const float4* __restrict__ ar  = tgt   + (size_t)rc * 64;  // block-uniform
        const float*  __restrict__ aar = areaT + (size_t)rc * 64;

        float csum = 0.0f;
#pragma unroll 8
        for (int j = 0; j < 64; ++j) {
            if (!((rm >> j) & 1ull)) continue;          // vi=0 rows: uniform skip
            float4 a  = ar[j];                          // s_load (broadcast)
            float  aA = aar[j];
            float ltx = fmaxf(a.x, b.x), lty = fmaxf(a.y, b.y);
            float rbx = fminf(a.z, b.z), rby = fminf(a.w, b.w);
            float w = fmaxf(rbx - ltx, 0.0f), h = fmaxf(rby - lty, 0.0f);
            float inter = w * h;
            float uni = aA + aB - inter;
            float cx1 = fminf(a.x, b.x), cy1 = fminf(a.y, b.y);
            float cx2 = fmaxf(a.z, b.z), cy2 = fmaxf(a.w, b.w);
            float areaC = (cx2 - cx1) * (cy2 - cy1);
            float hval = fmaf(uni, fastrcp(areaC), inter * fastrcp(uni));
            csum += hval;                               // vi==1 when bit set
        }
        colpart[(size_t)rc * M + c] = csum;             // coalesced 4B
    }
}

// ---------------- combine partials -----------------------------------------
__global__ __launch_bounds__(TPB) void reduce_kernel(
        const unsigned long long* __restrict__ keypart,
        const float* __restrict__ colpart, int M, int C,
        int* __restrict__ idx, float* __restrict__ colsumh) {
    int m = blockIdx.x * blockDim.x + threadIdx.x;
    if (m >= M) return;
    unsigned long long k = keypart[m];
    float s = colpart[m];
    for (int cc = 1; cc < C; ++cc) {
        unsigned long long kc = keypart[(size_t)cc * M + m];
        k = (kc > k) ? kc : k;
        s += colpart[(size_t)cc * M + m];
    }
    idx[m] = (int)(~(unsigned)k);
    colsumh[m] = s;
}

// ---------------- finalize: all scalar reductions, 1 block -----------------
__device__ __forceinline__ double wave_sum_d(double x) {
    for (int off = 32; off >= 1; off >>= 1) x += __shfl_xor(x, off);
    return x;
}

__global__ __launch_bounds__(FTPB) void finalize_kernel(
        const float4* __restrict__ convS, const float4* __restrict__ tgt,
        const float* __restrict__ vv, const int* __restrict__ idx,
        const float* __restrict__ colsumh, int M, float* __restrict__ out) {
    __shared__ double red[4 * (FTPB / WAVE)];
    const int tid = threadIdx.x;

    double sumV = 0.0, S2 = 0.0, S1h = 0.0, bbox = 0.0;
    for (int m = tid; m < M; m += FTPB) {
        float vi = vv[m];
        int   k  = idx[m];
        float vk = vv[k];
        sumV += (double)vi;
        S2   += (double)vk;
        S1h  += (double)vk * (double)colsumh[k];
        float4 s = convS[k];
        float4 t = tgt[m];
        bbox += (double)vi * (double)(fabsf(s.x - t.x) + fabsf(s.y - t.y) +
                                      fabsf(s.z - t.z) + fabsf(s.w - t.w));
    }
    sumV = wave_sum_d(sumV);
    S2   = wave_sum_d(S2);
    S1h  = wave_sum_d(S1h);
    bbox = wave_sum_d(bbox);
    int wid = tid >> 6, lane = tid & (WAVE - 1);
    const int NW = FTPB / WAVE;
    if (lane == 0) {
        red[wid] = sumV; red[NW + wid] = S2; red[2 * NW + wid] = S1h; red[3 * NW + wid] = bbox;
    }
    __syncthreads();
    if (tid == 0) {
        double a = 0, b = 0, c = 0, d = 0;
        for (int w = 0; w < NW; ++w) {
            a += red[w]; b += red[NW + w]; c += red[2 * NW + w]; d += red[3 * NW + w];
        }
        // colsum_g = colsum_h - sumV  =>  loss_giou = 2 - S1h/(sumV*S2)
        out[0] = (float)(2.0 - c / (a * b));
        out[1] = (float)(d / (4.0 * a));
    }
}

// ---------------------------------------------------------------------------
extern "C" void kernel_launch(void* const* d_in, const int* in_sizes, int n_in,
                              void* d_out, int out_size, void* d_ws, size_t ws_size,
                              hipStream_t stream) {
    const float4* pred = (const float4*)d_in[0];
    const float4* tgt  = (const float4*)d_in[1];
    const void*   mask = d_in[2];

    int M = in_sizes[0] / 4;        // 4096 (B*T*N); multiple of 256
    int N = M / in_sizes[2];        // boxes per mask entry (8)
    int nsh = -1;
    for (int s = 0; s < 31; ++s) if ((1 << s) == N) { nsh = s; break; }

    int C = M >> 6;                 // 64-wide chunks

    char* ws = (char*)d_ws;
    float4* convS   = (float4*)ws;             ws += (size_t)M * 16;
    float*  areaS   = (float*)ws;              ws += (size_t)M * 4;
    float*  areaT   = (float*)ws;              ws += (size_t)M * 4;
    float*  vv      = (float*)ws;              ws += (size_t)M * 4;
    unsigned long long* cmaskp = (unsigned long long*)ws; ws += (size_t)C * 8;
    unsigned long long* keypart = (unsigned long long*)ws; ws += (size_t)C * M * 8;
    float*  colpart = (float*)ws;              ws += (size_t)C * M * 4;
    int*    idx     = (int*)ws;                ws += (size_t)M * 4;
    float*  colsumh = (float*)ws;              ws += (size_t)M * 4;
    float*  out = (float*)d_out;

    prep_kernel<<<(M + TPB - 1) / TPB, TPB, 0, stream>>>(
        pred, tgt, mask, M, nsh, N, convS, areaS, areaT, vv, cmaskp);

    int rowBlocks = (M / TPB) * C;              // 16 * 64 = 1024
    int colBlocks = rowBlocks;
    pass_kernel<<<rowBlocks + colBlocks, TPB, 0, stream>>>(
        tgt, areaT, convS, areaS, cmaskp, M, rowBlocks, keypart, colpart);

    reduce_kernel<<<(M + TPB - 1) / TPB, TPB, 0, stream>>>(
        keypart, colpart, M, C, idx, colsumh);

    finalize_kernel<<<1, FTPB, 0, stream>>>(convS, tgt, vv, idx, colsumh, M, out);
}